// Round 1
// baseline (184.090 us; speedup 1.0000x reference)
//
#include <hip/hip_runtime.h>
#include <math.h>

// Problem constants (fixed by setup_inputs)
#define N_S   1024
#define N_T   1024
#define C_IN  128
#define E_EDG 16384
#define R     32
#define NSTEP 2

// ---------------------------------------------------------------------------
// G[a,b] = sum_c W1[a,c]*W1[b,c] + W2[a,c]*W2[b,c]   (W1,W2: [128,256])
// ---------------------------------------------------------------------------
__global__ __launch_bounds__(128) void k_gram(const float* __restrict__ W1,
                                              const float* __restrict__ W2,
                                              float* __restrict__ G) {
    int a = blockIdx.x;      // 128 blocks
    int b = threadIdx.x;     // 128 threads
    __shared__ float wa[512];
    for (int c = threadIdx.x; c < 256; c += 128) {
        wa[c]       = W1[a * 256 + c];
        wa[256 + c] = W2[a * 256 + c];
    }
    __syncthreads();
    float acc = 0.f;
    for (int c = 0; c < 256; ++c)
        acc += wa[c] * W1[b * 256 + c] + wa[256 + c] * W2[b * 256 + c];
    G[a * 128 + b] = acc;
}

// ---------------------------------------------------------------------------
// Ys[i,a] = sum_d inputs[idx1[i],d] * G[d,a]
// ---------------------------------------------------------------------------
__global__ __launch_bounds__(128) void k_ys(const float* __restrict__ X,
                                            const int* __restrict__ idx1,
                                            const float* __restrict__ G,
                                            float* __restrict__ Ys) {
    int i = blockIdx.x;      // 1024
    int a = threadIdx.x;     // 128
    __shared__ float x[128];
    int row = idx1[i];
    x[a] = X[row * 128 + a];
    __syncthreads();
    float acc = 0.f;
#pragma unroll 8
    for (int d = 0; d < 128; ++d)
        acc += x[d] * G[d * 128 + a];
    Ys[i * 128 + a] = acc;
}

// ---------------------------------------------------------------------------
// Shat[i,j] = sum_d Ys[i,d] * inputs[idx2[j],d]   (64x64 tile / block)
// ---------------------------------------------------------------------------
__global__ __launch_bounds__(256) void k_shat(const float* __restrict__ Ys,
                                              const float* __restrict__ X,
                                              const int* __restrict__ idx2,
                                              float* __restrict__ Shat) {
    __shared__ float As[64][132];   // 132: float4-aligned, conflict-benign pad
    __shared__ float Bs[64][132];
    const int i0 = blockIdx.y * 64, j0 = blockIdx.x * 64;
    const int t = threadIdx.x;
    for (int s = t; s < 64 * 32; s += 256) {            // 64 rows x 32 float4
        int row = s >> 5, q = s & 31;
        float4 v = ((const float4*)(Ys + (size_t)(i0 + row) * 128))[q];
        *(float4*)&As[row][q * 4] = v;
    }
    for (int s = t; s < 64 * 32; s += 256) {
        int row = s >> 5, q = s & 31;
        int src = idx2[j0 + row];
        float4 v = ((const float4*)(X + (size_t)src * 128))[q];
        *(float4*)&Bs[row][q * 4] = v;
    }
    __syncthreads();
    const int r = t >> 4, c = t & 15;   // lanes contiguous in j for coalesced store
    float acc[4][4] = {};
    for (int k = 0; k < 128; k += 4) {
        float4 ya[4], xb[4];
#pragma unroll
        for (int a = 0; a < 4; ++a) ya[a] = *(const float4*)&As[r + 16 * a][k];
#pragma unroll
        for (int b = 0; b < 4; ++b) xb[b] = *(const float4*)&Bs[c + 16 * b][k];
#pragma unroll
        for (int a = 0; a < 4; ++a)
#pragma unroll
            for (int b = 0; b < 4; ++b)
                acc[a][b] += ya[a].x * xb[b].x + ya[a].y * xb[b].y +
                             ya[a].z * xb[b].z + ya[a].w * xb[b].w;
    }
#pragma unroll
    for (int a = 0; a < 4; ++a)
#pragma unroll
        for (int b = 0; b < 4; ++b)
            Shat[(size_t)(i0 + r + 16 * a) * 1024 + (j0 + c + 16 * b)] = acc[a][b];
}

// ---------------------------------------------------------------------------
// Row softmax: Sdst[i,:] = softmax(Shat[i,:]); optionally duplicate to out0
// ---------------------------------------------------------------------------
__global__ __launch_bounds__(256) void k_softmax(const float* __restrict__ Shat,
                                                 float* __restrict__ Sdst,
                                                 float* __restrict__ out0) {
    int i = blockIdx.x;
    int t = threadIdx.x;
    const float* row = Shat + (size_t)i * 1024;
    float x[4];
#pragma unroll
    for (int j = 0; j < 4; ++j) x[j] = row[t + 256 * j];
    __shared__ float red[256];
    float m = fmaxf(fmaxf(x[0], x[1]), fmaxf(x[2], x[3]));
    red[t] = m;
    __syncthreads();
    for (int s = 128; s > 0; s >>= 1) {
        if (t < s) red[t] = fmaxf(red[t], red[t + s]);
        __syncthreads();
    }
    float rowmax = red[0];
    __syncthreads();
    float e[4], sum = 0.f;
#pragma unroll
    for (int j = 0; j < 4; ++j) { e[j] = expf(x[j] - rowmax); sum += e[j]; }
    red[t] = sum;
    __syncthreads();
    for (int s = 128; s > 0; s >>= 1) {
        if (t < s) red[t] += red[t + s];
        __syncthreads();
    }
    float inv = 1.f / red[0];
#pragma unroll
    for (int j = 0; j < 4; ++j) {
        float v = e[j] * inv;
        Sdst[(size_t)i * 1024 + t + 256 * j] = v;
        if (out0) out0[(size_t)i * 1024 + t + 256 * j] = v;
    }
}

// ---------------------------------------------------------------------------
// rt[j,k] += sum_{i in chunk} S[i,j] * rs[i,k]    (atomic partial sums)
// grid: (16 j-tiles of 64, 8 i-chunks of 128), block 256
// ---------------------------------------------------------------------------
__global__ __launch_bounds__(256) void k_rt(const float* __restrict__ S,
                                            const float* __restrict__ rs,
                                            float* __restrict__ rt) {
    int j0 = blockIdx.x * 64;
    int i0 = blockIdx.y * 128;
    int t = threadIdx.x;
    int k = t & 31;
    int jg = t >> 5;   // 0..7 -> owns j_local jg*8 .. jg*8+7
    __shared__ float Sl[16][68];
    __shared__ float Rl[16][36];
    float acc[8] = {};
    for (int ic = 0; ic < 128; ic += 16) {
        for (int s = t; s < 16 * 16; s += 256) {  // 16 rows x 16 float4 (64 cols)
            int row = s >> 4, q = s & 15;
            *(float4*)&Sl[row][q * 4] =
                ((const float4*)(S + (size_t)(i0 + ic + row) * 1024 + j0))[q];
        }
        for (int s = t; s < 16 * 8; s += 256) {   // 16 rows x 8 float4 (32 cols)
            int row = s >> 3, q = s & 7;
            *(float4*)&Rl[row][q * 4] =
                ((const float4*)(rs + (size_t)(i0 + ic + row) * 32))[q];
        }
        __syncthreads();
#pragma unroll
        for (int ii = 0; ii < 16; ++ii) {
            float rv = Rl[ii][k];
#pragma unroll
            for (int m = 0; m < 8; ++m)
                acc[m] += Sl[ii][jg * 8 + m] * rv;
        }
        __syncthreads();
    }
#pragma unroll
    for (int m = 0; m < 8; ++m)
        atomicAdd(&rt[(size_t)(j0 + jg * 8 + m) * 32 + k], acc[m]);
}

// ---------------------------------------------------------------------------
// Scatter-add neighbor aggregation for both graphs.
// gid = (edge,channel); first E*32 -> graph s, next E*32 -> graph t
// ---------------------------------------------------------------------------
__global__ __launch_bounds__(256) void k_scatter(const int* __restrict__ es,
                                                 const int* __restrict__ et,
                                                 const float* __restrict__ rs,
                                                 const float* __restrict__ rt,
                                                 float* __restrict__ aggs,
                                                 float* __restrict__ aggt) {
    int gid = blockIdx.x * 256 + threadIdx.x;
    int k = gid & 31;
    int e = gid >> 5;
    if (e < E_EDG) {
        int src = es[e], dst = es[E_EDG + e];
        atomicAdd(&aggs[(size_t)dst * 32 + k], rs[(size_t)src * 32 + k]);
    } else {
        e -= E_EDG;
        int src = et[e], dst = et[E_EDG + e];
        atomicAdd(&aggt[(size_t)dst * 32 + k], rt[(size_t)src * 32 + k]);
    }
}

// ---------------------------------------------------------------------------
// o = relu((r+agg) @ W3 + b3);  P = o_s@Wm1 + bm1;  Q = o_t@Wm1
// 8 rows per block (32 lanes per row). Blocks 0..127 -> s, 128..255 -> t.
// ---------------------------------------------------------------------------
__global__ __launch_bounds__(256) void k_post(const float* __restrict__ rs,
                                              const float* __restrict__ rt,
                                              const float* __restrict__ aggs,
                                              const float* __restrict__ aggt,
                                              const float* __restrict__ W3,
                                              const float* __restrict__ b3,
                                              const float* __restrict__ Wm1,
                                              const float* __restrict__ bm1,
                                              float* __restrict__ P,
                                              float* __restrict__ Q) {
    __shared__ float w3[1024], wm1[1024];
    __shared__ float ul[8][33], ol[8][33];
    int t = threadIdx.x;
    for (int s = t; s < 1024; s += 256) { w3[s] = W3[s]; wm1[s] = Wm1[s]; }
    int row8 = t >> 5, k = t & 31;
    int grow = blockIdx.x * 8 + row8;            // 0..2047
    bool is_s = grow < 1024;
    int r = is_s ? grow : grow - 1024;
    const float* rin = is_s ? rs : rt;
    const float* agg = is_s ? aggs : aggt;
    ul[row8][k] = rin[(size_t)r * 32 + k] + agg[(size_t)r * 32 + k];
    __syncthreads();
    float acc = b3[k];
#pragma unroll
    for (int m = 0; m < 32; ++m) acc += ul[row8][m] * w3[m * 32 + k];
    ol[row8][k] = fmaxf(acc, 0.f);
    __syncthreads();
    float acc2 = is_s ? bm1[k] : 0.f;
#pragma unroll
    for (int m = 0; m < 32; ++m) acc2 += ol[row8][m] * wm1[m * 32 + k];
    if (is_s) P[(size_t)r * 32 + k] = acc2;
    else      Q[(size_t)r * 32 + k] = acc2;
}

// ---------------------------------------------------------------------------
// Shat[i,j] += bm2 + sum_k Wm2[k] * relu(P[i,k] - Q[j,k])   (64x64 tile/block)
// ---------------------------------------------------------------------------
__global__ __launch_bounds__(256) void k_delta(const float* __restrict__ P,
                                               const float* __restrict__ Q,
                                               const float* __restrict__ Wm2,
                                               const float* __restrict__ bm2,
                                               float* __restrict__ Shat) {
    __shared__ float Pl[64][36], Ql[64][36];
    int t = threadIdx.x;
    int i0 = blockIdx.y * 64, j0 = blockIdx.x * 64;
    for (int s = t; s < 64 * 8; s += 256) {  // 64 rows x 8 float4 (32 cols)
        int row = s >> 3, q = s & 7;
        *(float4*)&Pl[row][q * 4] = ((const float4*)(P + (size_t)(i0 + row) * 32))[q];
        *(float4*)&Ql[row][q * 4] = ((const float4*)(Q + (size_t)(j0 + row) * 32))[q];
    }
    __syncthreads();
    int r = t >> 4, c = t & 15;
    float bv = bm2[0];
    float acc[4][4] = {};
#pragma unroll
    for (int q = 0; q < 8; ++q) {
        float4 w = ((const float4*)Wm2)[q];
        float4 pa[4], qb[4];
#pragma unroll
        for (int a = 0; a < 4; ++a) pa[a] = *(const float4*)&Pl[r + 16 * a][q * 4];
#pragma unroll
        for (int b = 0; b < 4; ++b) qb[b] = *(const float4*)&Ql[c + 16 * b][q * 4];
#pragma unroll
        for (int a = 0; a < 4; ++a)
#pragma unroll
            for (int b = 0; b < 4; ++b)
                acc[a][b] += w.x * fmaxf(pa[a].x - qb[b].x, 0.f)
                           + w.y * fmaxf(pa[a].y - qb[b].y, 0.f)
                           + w.z * fmaxf(pa[a].z - qb[b].z, 0.f)
                           + w.w * fmaxf(pa[a].w - qb[b].w, 0.f);
    }
#pragma unroll
    for (int a = 0; a < 4; ++a)
#pragma unroll
        for (int b = 0; b < 4; ++b) {
            size_t idx = (size_t)(i0 + r + 16 * a) * 1024 + (j0 + c + 16 * b);
            Shat[idx] += acc[a][b] + bv;
        }
}

// ---------------------------------------------------------------------------
extern "C" void kernel_launch(void* const* d_in, const int* in_sizes, int n_in,
                              void* d_out, int out_size, void* d_ws, size_t ws_size,
                              hipStream_t stream) {
    const float* inputs = (const float*)d_in[0];
    const int*   idx1   = (const int*)d_in[1];
    const int*   idx2   = (const int*)d_in[2];
    const int*   es     = (const int*)d_in[3];
    const int*   et     = (const int*)d_in[4];
    const float* W1     = (const float*)d_in[5];
    const float* W2     = (const float*)d_in[6];
    const float* W3     = (const float*)d_in[7];
    const float* b3     = (const float*)d_in[8];
    const float* Wm1    = (const float*)d_in[9];
    const float* bm1    = (const float*)d_in[10];
    const float* Wm2    = (const float*)d_in[11];
    const float* bm2    = (const float*)d_in[12];
    const float* rs_all = (const float*)d_in[13];
    float* out = (float*)d_out;
    float* ws  = (float*)d_ws;

    // workspace layout (floats)
    float* Shat = ws;                    // 1,048,576
    float* S    = Shat + (1 << 20);      // 1,048,576
    float* Ys   = S + (1 << 20);         // 131,072
    float* G    = Ys + 131072;           // 16,384
    float* rt   = G + 16384;             // 32,768   (rt, aggs, aggt contiguous -> one memset)
    float* aggs = rt + 32768;            // 32,768
    float* aggt = aggs + 32768;          // 32,768
    float* P    = aggt + 32768;          // 32,768
    float* Q    = P + 32768;             // 32,768

    k_gram<<<128, 128, 0, stream>>>(W1, W2, G);
    k_ys<<<1024, 128, 0, stream>>>(inputs, idx1, G, Ys);
    k_shat<<<dim3(16, 16), 256, 0, stream>>>(Ys, inputs, idx2, Shat);

    for (int step = 0; step < NSTEP; ++step) {
        const float* rs = rs_all + (size_t)step * N_S * R;
        hipMemsetAsync(rt, 0, 3 * 32768 * sizeof(float), stream);
        k_softmax<<<1024, 256, 0, stream>>>(Shat, S, step == 0 ? out : nullptr);
        k_rt<<<dim3(16, 8), 256, 0, stream>>>(S, rs, rt);
        k_scatter<<<4096, 256, 0, stream>>>(es, et, rs, rt, aggs, aggt);
        k_post<<<256, 256, 0, stream>>>(rs, rt, aggs, aggt, W3, b3, Wm1, bm1, P, Q);
        k_delta<<<dim3(16, 16), 256, 0, stream>>>(P, Q, Wm2, bm2, Shat);
    }
    k_softmax<<<1024, 256, 0, stream>>>(Shat, out + (1 << 20), nullptr);
}